// Round 1
// baseline (269.071 us; speedup 1.0000x reference)
//
#include <hip/hip_runtime.h>

#define EPSF 1e-6f

typedef _Float16 half8 __attribute__((ext_vector_type(8)));
typedef float f32x4 __attribute__((ext_vector_type(4)));

constexpr int B = 128, L = 512, S = 512, C = 64;
constexpr int TILE_R = 64;            // rows per pass-1 block
constexpr int TILES  = L / TILE_R;    // 8
constexpr int CHUNK  = 64;            // cols per k-chunk
constexpr int NCHUNK = S / CHUNK;     // 8
constexpr int HALVES = 2;             // S-split: each block does NCHUNK/HALVES chunks
constexpr int CPB    = NCHUNK / HALVES;   // 4 chunks per block

// workspace float offsets (row stats are per-half partials)
constexpr size_t WS_COLMAX = 0;
constexpr size_t WS_COLSUM = WS_COLMAX + (size_t)B * TILES * S;
constexpr size_t WS_COLSSQ = WS_COLSUM + (size_t)B * TILES * S;
constexpr size_t WS_COLP1  = WS_COLSSQ + (size_t)B * TILES * S;
constexpr size_t WS_ROWMAX = WS_COLP1  + (size_t)B * TILES * S;
constexpr size_t WS_ROWSUM = WS_ROWMAX + (size_t)B * L * HALVES;
constexpr size_t WS_ROWSSQ = WS_ROWSUM + (size_t)B * L * HALVES;
constexpr size_t WS_ROWP2  = WS_ROWSSQ + (size_t)B * L * HALVES;
constexpr size_t WS_NEGS   = WS_ROWP2  + (size_t)B * L * HALVES;
constexpr size_t WS_NEGC   = WS_NEGS   + (size_t)B * TILES * HALVES;
// frag-swizzled fp16 hi/lo planes. Per (b,tile): 2 planes x 8 idx x 64 lanes
// of half8 = 1024 half8 = 4096 floats. Total +33.6 MB of workspace.
constexpr size_t WS_QF     = WS_NEGC   + (size_t)B * TILES * HALVES;
constexpr size_t WS_KF     = WS_QF     + (size_t)B * TILES * 4096;
// end = WS_KF + B*NCHUNK*4096 floats  (~44 MB total)

// Load a thread's 16 consecutive floats of a 64x64 tile: row = t>>2, c0 = (t&3)*16.
__device__ inline void loadTile(const float* __restrict__ g, float4 v[4], int t)
{
    const float* src = g + (t >> 2) * 64 + (t & 3) * 16;
    v[0] = *(const float4*)(src);
    v[1] = *(const float4*)(src + 4);
    v[2] = *(const float4*)(src + 8);
    v[3] = *(const float4*)(src + 12);
}

// Write regs into frag-swizzled fp16 hi/lo GLOBAL planes (byte-identical layout
// to the previous LDS stageW): dst[(row>>4)*2 + (c>>5)][(((c>>3)&3)<<4)+(row&15)]
// so a wave's fragment read is one lane-linear global_load_dwordx4.
__device__ inline void fragStore(const float4 v4[4], half8* dhi, half8* dlo, int t)
{
    const int row = t >> 2, c0 = (t & 3) * 16;
    const float v[16] = {v4[0].x, v4[0].y, v4[0].z, v4[0].w, v4[1].x, v4[1].y, v4[1].z, v4[1].w,
                         v4[2].x, v4[2].y, v4[2].z, v4[2].w, v4[3].x, v4[3].y, v4[3].z, v4[3].w};
#pragma unroll
    for (int o = 0; o < 2; ++o) {
        const int cb     = c0 + o * 8;
        const int idx    = (row >> 4) * 2 + (cb >> 5);
        const int lane_s = (((cb >> 3) & 3) << 4) + (row & 15);
        half8 h, l;
#pragma unroll
        for (int j = 0; j < 8; ++j) {
            float f = v[o * 8 + j];
            _Float16 hi = (_Float16)f;
            h[j] = hi;
            l[j] = (_Float16)(f - (float)hi);
        }
        dhi[idx * 64 + lane_s] = h;
        dlo[idx * 64 + lane_s] = l;
    }
}

// Pre-pass: convert q and k ONCE into frag-ready hi/lo fp16 planes.
// Memory-bound (~67 MB traffic); removes all conversion VALU + staging barriers
// from pass1's hot loop (k was previously re-converted by all 8 tile-blocks).
__global__ __launch_bounds__(256)
void convert_kernel(const float* __restrict__ q, const float* __restrict__ kmat,
                    float* __restrict__ ws)
{
    const int bidx = blockIdx.x;
    const int b    = bidx >> 4;          // 16 jobs per b: 8 q-tiles + 8 k-chunks
    const int t16  = bidx & 15;
    const int tid  = threadIdx.x;
    const bool isq = (t16 < TILES);
    const int tile = isq ? t16 : t16 - TILES;

    const float* src = isq ? (q    + ((size_t)b * L + (size_t)tile * TILE_R) * C)
                           : (kmat + ((size_t)b * S + (size_t)tile * CHUNK)  * C);
    half8* base = (half8*)(ws + (isq ? WS_QF : WS_KF)) + (size_t)(b * TILES + tile) * 1024;

    float4 v[4];
    loadTile(src, v, tid);
    fragStore(v, base, base + 512, tid);
}

// REGISTER/OCCUPANCY MODEL (measured R8-R12): effective per-SIMD VGPR pool is
// 256; live set <= 85 regs -> 3 waves/SIMD. waves_per_eu(3,8): cap floor(256/3)=85.
// This version drops the tv[4] staging regs and all LDS k-staging: only
// colred4 (16 KB) + nred remain in LDS, and the chunk loop has NO barriers.
__global__ __launch_bounds__(256) __attribute__((amdgpu_waves_per_eu(3, 8)))
void pass1_kernel(const int* __restrict__ labels, float* __restrict__ ws)
{
    __shared__ float4 colred4[4][CPB][CHUNK];   // 16 KB per-wave column partials
    __shared__ float nred[4][2];

    const int bidx = blockIdx.x;
    const int b    = bidx / (TILES * HALVES);
    const int rem  = bidx % (TILES * HALVES);
    const int tile = rem >> 1;
    const int half = rem & 1;
    const int chbase = half * CPB;
    const int tid  = threadIdx.x;
    const int lane = tid & 63;
    const int wave = tid >> 6;
    const int l15  = lane & 15;
    const int quad = lane >> 4;
    const int rowbase = tile * TILE_R;

    float* colmax_p = ws + WS_COLMAX;
    float* colsum_p = ws + WS_COLSUM;
    float* colssq_p = ws + WS_COLSSQ;
    float* colp1_p  = ws + WS_COLP1;
    float* rowmax_p = ws + WS_ROWMAX;
    float* rowsum_p = ws + WS_ROWSUM;
    float* rowssq_p = ws + WS_ROWSSQ;
    float* rowp2_p  = ws + WS_ROWP2;
    float* negs_p   = ws + WS_NEGS;
    float* negc_p   = ws + WS_NEGC;

    const int* lb = labels + ((size_t)b * L + rowbase) * S;

    const half8* qf  = (const half8*)(ws + WS_QF) + (size_t)(b * TILES + tile) * 1024;
    const half8* kf0 = (const half8*)(ws + WS_KF) + (size_t)b * NCHUNK * 1024;

    // A fragments: direct coalesced loads from the precomputed planes
    half8 ah0 = qf[(wave * 2 + 0) * 64 + lane];
    half8 ah1 = qf[(wave * 2 + 1) * 64 + lane];
    half8 al0 = qf[512 + (wave * 2 + 0) * 64 + lane];
    half8 al1 = qf[512 + (wave * 2 + 1) * 64 + lane];

    // labels for first chunk (nontemporal: 134 MB stream must not evict k frags
    // from L2 — frags are reused by the 8 tile-blocks of each b)
    int labn[16];
#pragma unroll
    for (int ct = 0; ct < 4; ++ct)
#pragma unroll
        for (int r = 0; r < 4; ++r)
            labn[ct * 4 + r] = __builtin_nontemporal_load(
                &lb[(size_t)(wave * 16 + quad * 4 + r) * S + chbase * CHUNK + ct * 16 + l15]);

    float rmax[4], rsum[4], rssq[4], rp2[4];
#pragma unroll
    for (int i = 0; i < 4; ++i) { rmax[i] = -3.4e38f; rsum[i] = 0.f; rssq[i] = 0.f; rp2[i] = 0.f; }
    float negsum = 0.f;
    int   possum = 0;

    for (int c4 = 0; c4 < CPB; ++c4) {
        const int ch = chbase + c4;
        const half8* kfc = kf0 + (size_t)ch * 1024;

        f32x4 acc[4];
#pragma unroll
        for (int ct = 0; ct < 4; ++ct) {
            half8 bh0 = kfc[(ct * 2 + 0) * 64 + lane];
            half8 bh1 = kfc[(ct * 2 + 1) * 64 + lane];
            half8 bl0 = kfc[512 + (ct * 2 + 0) * 64 + lane];
            half8 bl1 = kfc[512 + (ct * 2 + 1) * 64 + lane];
            f32x4 a = {0.f, 0.f, 0.f, 0.f};
            a = __builtin_amdgcn_mfma_f32_16x16x32_f16(ah0, bh0, a, 0, 0, 0);
            a = __builtin_amdgcn_mfma_f32_16x16x32_f16(ah0, bl0, a, 0, 0, 0);
            a = __builtin_amdgcn_mfma_f32_16x16x32_f16(al0, bh0, a, 0, 0, 0);
            a = __builtin_amdgcn_mfma_f32_16x16x32_f16(ah1, bh1, a, 0, 0, 0);
            a = __builtin_amdgcn_mfma_f32_16x16x32_f16(ah1, bl1, a, 0, 0, 0);
            a = __builtin_amdgcn_mfma_f32_16x16x32_f16(al1, bh1, a, 0, 0, 0);
            acc[ct] = a;
        }

        // epilogue: C/D layout col = l15, row = quad*4 + r  [m89-verified]
#pragma unroll
        for (int ct = 0; ct < 4; ++ct) {
            float cmax = -3.4e38f, csum = 0.f, cssq = 0.f, cp1 = 0.f;
#pragma unroll
            for (int r = 0; r < 4; ++r) {
                int lab = labn[ct * 4 + r];
                float sim = fmaf(0.5f, acc[ct][r], 0.5f);
                rmax[r] = fmaxf(rmax[r], sim);
                rsum[r] += sim;
                rssq[r] = fmaf(sim, sim, rssq[r]);
                cmax = fmaxf(cmax, sim);
                csum += sim;
                cssq = fmaf(sim, sim, cssq);
                float sc  = fminf(fmaxf(sim, EPSF), 1.f - EPSF);
                bool  isp = (lab == 1);
                float pos = isp ? 1.f : 0.f;
                float t   = isp ? sc : (1.f - sc);
                float nl  = -__logf(t);      // one log per element
                float pn  = pos * nl;
                rp2[r] += pn;
                cp1 += pn;
                negsum += nl - pn;           // adds nl only when neg
                possum += lab;               // negcnt derived at the end
            }
            // column reduce across quads (lanes sharing l15): xor 16, 32
#pragma unroll
            for (int m = 16; m <= 32; m <<= 1) {
                cmax = fmaxf(cmax, __shfl_xor(cmax, m, 64));
                csum += __shfl_xor(csum, m, 64);
                cssq += __shfl_xor(cssq, m, 64);
                cp1  += __shfl_xor(cp1,  m, 64);
            }
            if (lane < 16)
                colred4[wave][c4][ct * 16 + l15] = make_float4(cmax, csum, cssq, cp1);
        }

        // prefetch next chunk's labels AFTER consumption
        if (c4 + 1 < CPB) {
#pragma unroll
            for (int ct = 0; ct < 4; ++ct)
#pragma unroll
                for (int r = 0; r < 4; ++r)
                    labn[ct * 4 + r] = __builtin_nontemporal_load(
                        &lb[(size_t)(wave * 16 + quad * 4 + r) * S + (ch + 1) * CHUNK + ct * 16 + l15]);
        }
    }

    // ONE barrier for the whole kernel: publish per-wave column partials
    __syncthreads();
    {
        // 256 threads = (chunk, col) pairs: combine the 4 waves, store to global
        const int cc  = tid >> 6;      // chunk index 0..3
        const int col = tid & 63;
        float4 v = colred4[0][cc][col];
        float m0 = v.x, s1 = v.y, s2 = v.z, pp = v.w;
#pragma unroll
        for (int w = 1; w < 4; ++w) {
            float4 u = colred4[w][cc][col];
            m0 = fmaxf(m0, u.x); s1 += u.y; s2 += u.z; pp += u.w;
        }
        size_t idx = ((size_t)b * TILES + tile) * S + (chbase + cc) * CHUNK + col;
        colmax_p[idx] = m0; colsum_p[idx] = s1; colssq_p[idx] = s2; colp1_p[idx] = pp;
    }

    // row reduce across l15 (lanes sharing quad): xor 1,2,4,8 -> per-half partial
#pragma unroll
    for (int r = 0; r < 4; ++r) {
#pragma unroll
        for (int m = 1; m <= 8; m <<= 1) {
            rmax[r] = fmaxf(rmax[r], __shfl_xor(rmax[r], m, 64));
            rsum[r] += __shfl_xor(rsum[r], m, 64);
            rssq[r] += __shfl_xor(rssq[r], m, 64);
            rp2[r]  += __shfl_xor(rp2[r],  m, 64);
        }
    }
    if (l15 == 0) {
#pragma unroll
        for (int r = 0; r < 4; ++r) {
            size_t idx = ((size_t)b * L + rowbase + wave * 16 + quad * 4 + r) * HALVES + half;
            rowmax_p[idx] = rmax[r]; rowsum_p[idx] = rsum[r];
            rowssq_p[idx] = rssq[r]; rowp2_p[idx]  = rp2[r];
        }
    }

    // negatives: full block reduce (negcnt = elements - possum)
    float negcnt = (float)(16 * CPB - possum);
#pragma unroll
    for (int m = 1; m <= 32; m <<= 1) {
        negsum += __shfl_xor(negsum, m, 64);
        negcnt += __shfl_xor(negcnt, m, 64);
    }
    if (lane == 0) { nred[wave][0] = negsum; nred[wave][1] = negcnt; }
    __syncthreads();
    if (tid == 0) {
        float ns = 0.f, nc = 0.f;
        for (int w = 0; w < 4; ++w) { ns += nred[w][0]; nc += nred[w][1]; }
        negs_p[bidx] = ns; negc_p[bidx] = nc;
    }
}

template <bool MAX>
__device__ inline float bred(float v, float* red)
{
#pragma unroll
    for (int m = 1; m <= 32; m <<= 1) {
        float o = __shfl_xor(v, m, 64);
        v = MAX ? fmaxf(v, o) : (v + o);
    }
    const int wave = threadIdx.x >> 6;
    const int lane = threadIdx.x & 63;
    if (lane == 0) red[wave] = v;
    __syncthreads();
    if (threadIdx.x == 0) {
        float r = red[0];
        for (int w = 1; w < 8; ++w) r = MAX ? fmaxf(r, red[w]) : (r + red[w]);
        red[8] = r;
    }
    __syncthreads();
    float out = red[8];
    __syncthreads();   // protect red[] before next reduction reuses it
    return out;
}

// grid (B, 2): y==0 -> column path (sharp1 + loss1), y==1 -> row path (loss2 + loss3)
__global__ __launch_bounds__(512)
void pass2_kernel(const float* __restrict__ ws, float* __restrict__ out)
{
    __shared__ float red[9];
    const int b = blockIdx.x;
    const int s = threadIdx.x;

    if (blockIdx.y == 0) {
        const float* colmax_p = ws + WS_COLMAX;
        const float* colsum_p = ws + WS_COLSUM;
        const float* colssq_p = ws + WS_COLSSQ;
        const float* colp1_p  = ws + WS_COLP1;

        float m = -3.4e38f, sm = 0.f, sq = 0.f, p1 = 0.f;
#pragma unroll
        for (int t = 0; t < TILES; ++t) {
            size_t idx = ((size_t)b * TILES + t) * S + s;
            m = fmaxf(m, colmax_p[idx]);
            sm += colsum_p[idx];
            sq += colssq_p[idx];
            p1 += colp1_p[idx];
        }
        float mean  = sm * (1.f / L);
        float var   = (sq - sm * sm * (1.f / L)) * (1.f / (L - 1));
        float score = (m - mean) / sqrtf(var);

        float gmax = bred<true>(score, red);
        float e    = __expf(score - gmax);
        float esum = bred<false>(e, red);
        float sharp1 = e / esum;
        out[(size_t)b * S + s] = sharp1;
        float loss1 = bred<false>(sharp1 * p1, red);
        if (s == 0) atomicAdd(out + (size_t)B * S, loss1 * (0.5f / B));
    } else {
        const float* rowmax_p = ws + WS_ROWMAX;
        const float* rowsum_p = ws + WS_ROWSUM;
        const float* rowssq_p = ws + WS_ROWSSQ;
        const float* rowp2_p  = ws + WS_ROWP2;
        const float* negs_p   = ws + WS_NEGS;
        const float* negc_p   = ws + WS_NEGC;

        size_t ridx = ((size_t)b * L + s) * HALVES;
        float m2 = rowmax_p[ridx], sm2 = rowsum_p[ridx];
        float sq2 = rowssq_p[ridx], p2 = rowp2_p[ridx];
#pragma unroll
        for (int h = 1; h < HALVES; ++h) {
            m2 = fmaxf(m2, rowmax_p[ridx + h]);
            sm2 += rowsum_p[ridx + h];
            sq2 += rowssq_p[ridx + h];
            p2  += rowp2_p[ridx + h];
        }
        float mean2  = sm2 * (1.f / S);
        float var2   = (sq2 - sm2 * sm2 * (1.f / S)) * (1.f / (S - 1));
        float score2 = (m2 - mean2) / sqrtf(var2);

        float gmax2 = bred<true>(score2, red);
        float e2    = __expf(score2 - gmax2);
        float esum2 = bred<false>(e2, red);
        float loss2 = bred<false>((e2 / esum2) * p2, red);

        if (s == 0) {
            float ns = 0.f, nc = 0.f;
            for (int t = 0; t < TILES * HALVES; ++t) {
                ns += negs_p[b * TILES * HALVES + t];
                nc += negc_p[b * TILES * HALVES + t];
            }
            atomicAdd(out + (size_t)B * S, (0.5f * loss2 + ns / nc) * (1.f / B));
        }
    }
}

extern "C" void kernel_launch(void* const* d_in, const int* in_sizes, int n_in,
                              void* d_out, int out_size, void* d_ws, size_t ws_size,
                              hipStream_t stream)
{
    const float* q      = (const float*)d_in[0];
    const float* k      = (const float*)d_in[1];
    const int*   labels = (const int*)d_in[2];
    float* out = (float*)d_out;
    float* ws  = (float*)d_ws;

    // zero the scalar-loss slot (harness poisons d_out before timed replays)
    hipMemsetAsync((char*)d_out + (size_t)B * S * sizeof(float), 0, sizeof(float), stream);

    convert_kernel<<<dim3(B * (TILES + NCHUNK)), dim3(256), 0, stream>>>(q, k, ws);
    pass1_kernel<<<dim3(B * TILES * HALVES), dim3(256), 0, stream>>>(labels, ws);
    pass2_kernel<<<dim3(B, 2), dim3(512), 0, stream>>>(ws, out);
}

// Round 2
// 251.859 us; speedup vs baseline: 1.0683x; 1.0683x over previous
//
#include <hip/hip_runtime.h>

#define EPSF 1e-6f

typedef _Float16 half8 __attribute__((ext_vector_type(8)));
typedef float f32x4 __attribute__((ext_vector_type(4)));

constexpr int B = 128, L = 512, S = 512, C = 64;
constexpr int TILE_R = 64;            // rows per pass-1 block
constexpr int TILES  = L / TILE_R;    // 8
constexpr int CHUNK  = 64;            // cols per k-chunk
constexpr int NCHUNK = S / CHUNK;     // 8
constexpr int HALVES = 2;             // S-split: each block does NCHUNK/HALVES chunks
constexpr int CPB    = NCHUNK / HALVES;   // 4 chunks per block

// workspace float offsets (row stats are per-half partials)
constexpr size_t WS_COLMAX = 0;
constexpr size_t WS_COLSUM = WS_COLMAX + (size_t)B * TILES * S;
constexpr size_t WS_COLSSQ = WS_COLSUM + (size_t)B * TILES * S;
constexpr size_t WS_COLP1  = WS_COLSSQ + (size_t)B * TILES * S;
constexpr size_t WS_ROWMAX = WS_COLP1  + (size_t)B * TILES * S;
constexpr size_t WS_ROWSUM = WS_ROWMAX + (size_t)B * L * HALVES;
constexpr size_t WS_ROWSSQ = WS_ROWSUM + (size_t)B * L * HALVES;
constexpr size_t WS_ROWP2  = WS_ROWSSQ + (size_t)B * L * HALVES;
constexpr size_t WS_NEGS   = WS_ROWP2  + (size_t)B * L * HALVES;
constexpr size_t WS_NEGC   = WS_NEGS   + (size_t)B * TILES * HALVES;
// frag-swizzled fp16 hi/lo planes. Per (b,tile): 2 planes x 8 idx x 64 lanes
// of half8 = 1024 half8 = 4096 floats. Total +33.6 MB of workspace.
constexpr size_t WS_QF     = WS_NEGC   + (size_t)B * TILES * HALVES;
constexpr size_t WS_KF     = WS_QF     + (size_t)B * TILES * 4096;
// end = WS_KF + B*NCHUNK*4096 floats  (~44 MB total)

// Load a thread's 16 consecutive floats of a 64x64 tile: row = t>>2, c0 = (t&3)*16.
__device__ inline void loadTile(const float* __restrict__ g, float4 v[4], int t)
{
    const float* src = g + (t >> 2) * 64 + (t & 3) * 16;
    v[0] = *(const float4*)(src);
    v[1] = *(const float4*)(src + 4);
    v[2] = *(const float4*)(src + 8);
    v[3] = *(const float4*)(src + 12);
}

// Write regs into frag-swizzled fp16 hi/lo GLOBAL planes:
// dst[(row>>4)*2 + (c>>5)][(((c>>3)&3)<<4)+(row&15)] so a wave's fragment read
// is one lane-linear 16B access. Layout is also what global_load_lds reproduces
// in LDS (wave-uniform base + lane*16), since it is lane-linear.
__device__ inline void fragStore(const float4 v4[4], half8* dhi, half8* dlo, int t)
{
    const int row = t >> 2, c0 = (t & 3) * 16;
    const float v[16] = {v4[0].x, v4[0].y, v4[0].z, v4[0].w, v4[1].x, v4[1].y, v4[1].z, v4[1].w,
                         v4[2].x, v4[2].y, v4[2].z, v4[2].w, v4[3].x, v4[3].y, v4[3].z, v4[3].w};
#pragma unroll
    for (int o = 0; o < 2; ++o) {
        const int cb     = c0 + o * 8;
        const int idx    = (row >> 4) * 2 + (cb >> 5);
        const int lane_s = (((cb >> 3) & 3) << 4) + (row & 15);
        half8 h, l;
#pragma unroll
        for (int j = 0; j < 8; ++j) {
            float f = v[o * 8 + j];
            _Float16 hi = (_Float16)f;
            h[j] = hi;
            l[j] = (_Float16)(f - (float)hi);
        }
        dhi[idx * 64 + lane_s] = h;
        dlo[idx * 64 + lane_s] = l;
    }
}

// Pre-pass: convert q and k ONCE into frag-ready hi/lo fp16 planes.
__global__ __launch_bounds__(256)
void convert_kernel(const float* __restrict__ q, const float* __restrict__ kmat,
                    float* __restrict__ ws)
{
    const int bidx = blockIdx.x;
    const int b    = bidx >> 4;          // 16 jobs per b: 8 q-tiles + 8 k-chunks
    const int t16  = bidx & 15;
    const int tid  = threadIdx.x;
    const bool isq = (t16 < TILES);
    const int tile = isq ? t16 : t16 - TILES;

    const float* src = isq ? (q    + ((size_t)b * L + (size_t)tile * TILE_R) * C)
                           : (kmat + ((size_t)b * S + (size_t)tile * CHUNK)  * C);
    half8* base = (half8*)(ws + (isq ? WS_QF : WS_KF)) + (size_t)(b * TILES + tile) * 1024;

    float4 v[4];
    loadTile(src, v, tid);
    fragStore(v, base, base + 512, tid);
}

// async 16B global -> LDS copy (DMA path: no VGPR round trip, counted by vmcnt;
// __syncthreads() drains vmcnt so the per-chunk barrier doubles as the wait)
__device__ inline void gl16(const void* g, void* l)
{
    __builtin_amdgcn_global_load_lds((const __attribute__((address_space(1))) void*)g,
                                     (__attribute__((address_space(3))) void*)l, 16, 0, 0);
}

// REGISTER/OCCUPANCY MODEL: effective per-SIMD VGPR pool is 256; live set <= 85
// regs -> 3 waves/SIMD (waves_per_eu(3,8) caps alloc at 85). LDS 49.2 KB -> 3
// blocks/CU, matching the VGPR-derived occupancy.
// R1 lesson: B-frags read straight from global exposed ~500cyc L2/L3 latency
// per ct (VALUBusy fell 42->37, dur flat). This version DMA-stages the
// pre-converted frags into double-buffered LDS (prefetch one chunk ahead, one
// barrier per chunk) so ds_read_b128 (~12cyc tput) feeds the MFMAs instead.
__global__ __launch_bounds__(256) __attribute__((amdgpu_waves_per_eu(3, 8)))
void pass1_kernel(const int* __restrict__ labels, float* __restrict__ ws)
{
    __shared__ half8 kbuf[2][1024];             // 32 KB double-buffered B frags
    __shared__ float4 colred4[4][CPB][CHUNK];   // 16 KB per-wave column partials
    __shared__ float nred[4][2];

    const int bidx = blockIdx.x;
    const int b    = bidx / (TILES * HALVES);
    const int rem  = bidx % (TILES * HALVES);
    const int tile = rem >> 1;
    const int half = rem & 1;
    const int chbase = half * CPB;
    const int tid  = threadIdx.x;
    const int lane = tid & 63;
    const int wave = tid >> 6;
    const int l15  = lane & 15;
    const int quad = lane >> 4;
    const int rowbase = tile * TILE_R;

    float* colmax_p = ws + WS_COLMAX;
    float* colsum_p = ws + WS_COLSUM;
    float* colssq_p = ws + WS_COLSSQ;
    float* colp1_p  = ws + WS_COLP1;
    float* rowmax_p = ws + WS_ROWMAX;
    float* rowsum_p = ws + WS_ROWSUM;
    float* rowssq_p = ws + WS_ROWSSQ;
    float* rowp2_p  = ws + WS_ROWP2;
    float* negs_p   = ws + WS_NEGS;
    float* negc_p   = ws + WS_NEGC;

    const int* lb = labels + ((size_t)b * L + rowbase) * S;

    const half8* qf  = (const half8*)(ws + WS_QF) + (size_t)(b * TILES + tile) * 1024;
    const half8* kf0 = (const half8*)(ws + WS_KF) + (size_t)b * NCHUNK * 1024;

    // issue the 16KB frag block of chunk ch into kbuf[bi]: 4 instr/thread,
    // each wave DMAs 4x1KB. dst is wave-uniform (tid&192 = wave*64); HW adds
    // lane*16, matching the lane-linear global src.
    auto stage = [&](int ch, int bi) {
#pragma unroll
        for (int i = 0; i < 4; ++i)
            gl16(kf0 + (size_t)ch * 1024 + i * 256 + tid,
                 &kbuf[bi][i * 256 + (tid & 192)]);
    };

    stage(chbase, 0);   // chunk 0 in flight while we load A frags + labels

    // A fragments: direct coalesced loads from the precomputed planes
    half8 ah0 = qf[(wave * 2 + 0) * 64 + lane];
    half8 ah1 = qf[(wave * 2 + 1) * 64 + lane];
    half8 al0 = qf[512 + (wave * 2 + 0) * 64 + lane];
    half8 al1 = qf[512 + (wave * 2 + 1) * 64 + lane];

    // labels for first chunk (nontemporal: 134 MB stream must not evict frags)
    int labn[16];
#pragma unroll
    for (int ct = 0; ct < 4; ++ct)
#pragma unroll
        for (int r = 0; r < 4; ++r)
            labn[ct * 4 + r] = __builtin_nontemporal_load(
                &lb[(size_t)(wave * 16 + quad * 4 + r) * S + chbase * CHUNK + ct * 16 + l15]);

    float rmax[4], rsum[4], rssq[4], rp2[4];
#pragma unroll
    for (int i = 0; i < 4; ++i) { rmax[i] = -3.4e38f; rsum[i] = 0.f; rssq[i] = 0.f; rp2[i] = 0.f; }
    float negsum = 0.f;
    int   possum = 0;

    __syncthreads();   // drains vmcnt -> kbuf[0] ready

    for (int c4 = 0; c4 < CPB; ++c4) {
        const int ch = chbase + c4;
        if (c4 + 1 < CPB) stage(ch + 1, (c4 + 1) & 1);   // prefetch next chunk
        const half8* kb = kbuf[c4 & 1];

        f32x4 acc[4];
#pragma unroll
        for (int ct = 0; ct < 4; ++ct) {
            half8 bh0 = kb[(ct * 2 + 0) * 64 + lane];
            half8 bh1 = kb[(ct * 2 + 1) * 64 + lane];
            half8 bl0 = kb[512 + (ct * 2 + 0) * 64 + lane];
            half8 bl1 = kb[512 + (ct * 2 + 1) * 64 + lane];
            f32x4 a = {0.f, 0.f, 0.f, 0.f};
            a = __builtin_amdgcn_mfma_f32_16x16x32_f16(ah0, bh0, a, 0, 0, 0);
            a = __builtin_amdgcn_mfma_f32_16x16x32_f16(ah0, bl0, a, 0, 0, 0);
            a = __builtin_amdgcn_mfma_f32_16x16x32_f16(al0, bh0, a, 0, 0, 0);
            a = __builtin_amdgcn_mfma_f32_16x16x32_f16(ah1, bh1, a, 0, 0, 0);
            a = __builtin_amdgcn_mfma_f32_16x16x32_f16(ah1, bl1, a, 0, 0, 0);
            a = __builtin_amdgcn_mfma_f32_16x16x32_f16(al1, bh1, a, 0, 0, 0);
            acc[ct] = a;
        }

        // epilogue: C/D layout col = l15, row = quad*4 + r  [m89-verified]
#pragma unroll
        for (int ct = 0; ct < 4; ++ct) {
            float cmax = -3.4e38f, csum = 0.f, cssq = 0.f, cp1 = 0.f;
#pragma unroll
            for (int r = 0; r < 4; ++r) {
                int lab = labn[ct * 4 + r];
                float sim = fmaf(0.5f, acc[ct][r], 0.5f);
                rmax[r] = fmaxf(rmax[r], sim);
                rsum[r] += sim;
                rssq[r] = fmaf(sim, sim, rssq[r]);
                cmax = fmaxf(cmax, sim);
                csum += sim;
                cssq = fmaf(sim, sim, cssq);
                float sc  = fminf(fmaxf(sim, EPSF), 1.f - EPSF);
                bool  isp = (lab == 1);
                float pos = isp ? 1.f : 0.f;
                float t   = isp ? sc : (1.f - sc);
                float nl  = -__logf(t);      // one log per element
                float pn  = pos * nl;
                rp2[r] += pn;
                cp1 += pn;
                negsum += nl - pn;           // adds nl only when neg
                possum += lab;               // negcnt derived at the end
            }
            // column reduce across quads (lanes sharing l15): xor 16, 32
#pragma unroll
            for (int m = 16; m <= 32; m <<= 1) {
                cmax = fmaxf(cmax, __shfl_xor(cmax, m, 64));
                csum += __shfl_xor(csum, m, 64);
                cssq += __shfl_xor(cssq, m, 64);
                cp1  += __shfl_xor(cp1,  m, 64);
            }
            if (lane < 16)
                colred4[wave][c4][ct * 16 + l15] = make_float4(cmax, csum, cssq, cp1);
        }

        // prefetch next chunk's labels AFTER consumption (covered by next
        // chunk's MFMA+epilogue)
        if (c4 + 1 < CPB) {
#pragma unroll
            for (int ct = 0; ct < 4; ++ct)
#pragma unroll
                for (int r = 0; r < 4; ++r)
                    labn[ct * 4 + r] = __builtin_nontemporal_load(
                        &lb[(size_t)(wave * 16 + quad * 4 + r) * S + (ch + 1) * CHUNK + ct * 16 + l15]);
        }

        // one barrier per chunk: drains the async stage of chunk c4+1 AND
        // guarantees all waves finished ds_reads of kbuf[c4&1] before it is
        // re-staged in iter c4+2. Also publishes colred4 on the last iter.
        __syncthreads();
    }

    {   // 256 threads = (chunk, col) pairs: combine the 4 waves, store to global
        const int cc  = tid >> 6;      // chunk index 0..3
        const int col = tid & 63;
        float4 v = colred4[0][cc][col];
        float m0 = v.x, s1 = v.y, s2 = v.z, pp = v.w;
#pragma unroll
        for (int w = 1; w < 4; ++w) {
            float4 u = colred4[w][cc][col];
            m0 = fmaxf(m0, u.x); s1 += u.y; s2 += u.z; pp += u.w;
        }
        size_t idx = ((size_t)b * TILES + tile) * S + (chbase + cc) * CHUNK + col;
        colmax_p[idx] = m0; colsum_p[idx] = s1; colssq_p[idx] = s2; colp1_p[idx] = pp;
    }

    // row reduce across l15 (lanes sharing quad): xor 1,2,4,8 -> per-half partial
#pragma unroll
    for (int r = 0; r < 4; ++r) {
#pragma unroll
        for (int m = 1; m <= 8; m <<= 1) {
            rmax[r] = fmaxf(rmax[r], __shfl_xor(rmax[r], m, 64));
            rsum[r] += __shfl_xor(rsum[r], m, 64);
            rssq[r] += __shfl_xor(rssq[r], m, 64);
            rp2[r]  += __shfl_xor(rp2[r],  m, 64);
        }
    }
    if (l15 == 0) {
#pragma unroll
        for (int r = 0; r < 4; ++r) {
            size_t idx = ((size_t)b * L + rowbase + wave * 16 + quad * 4 + r) * HALVES + half;
            rowmax_p[idx] = rmax[r]; rowsum_p[idx] = rsum[r];
            rowssq_p[idx] = rssq[r]; rowp2_p[idx]  = rp2[r];
        }
    }

    // negatives: full block reduce (negcnt = elements - possum)
    float negcnt = (float)(16 * CPB - possum);
#pragma unroll
    for (int m = 1; m <= 32; m <<= 1) {
        negsum += __shfl_xor(negsum, m, 64);
        negcnt += __shfl_xor(negcnt, m, 64);
    }
    if (lane == 0) { nred[wave][0] = negsum; nred[wave][1] = negcnt; }
    __syncthreads();
    if (tid == 0) {
        float ns = 0.f, nc = 0.f;
        for (int w = 0; w < 4; ++w) { ns += nred[w][0]; nc += nred[w][1]; }
        negs_p[bidx] = ns; negc_p[bidx] = nc;
    }
}

template <bool MAX>
__device__ inline float bred(float v, float* red)
{
#pragma unroll
    for (int m = 1; m <= 32; m <<= 1) {
        float o = __shfl_xor(v, m, 64);
        v = MAX ? fmaxf(v, o) : (v + o);
    }
    const int wave = threadIdx.x >> 6;
    const int lane = threadIdx.x & 63;
    if (lane == 0) red[wave] = v;
    __syncthreads();
    if (threadIdx.x == 0) {
        float r = red[0];
        for (int w = 1; w < 8; ++w) r = MAX ? fmaxf(r, red[w]) : (r + red[w]);
        red[8] = r;
    }
    __syncthreads();
    float out = red[8];
    __syncthreads();   // protect red[] before next reduction reuses it
    return out;
}

// grid (B, 2): y==0 -> column path (sharp1 + loss1), y==1 -> row path (loss2 + loss3)
__global__ __launch_bounds__(512)
void pass2_kernel(const float* __restrict__ ws, float* __restrict__ out)
{
    __shared__ float red[9];
    const int b = blockIdx.x;
    const int s = threadIdx.x;

    if (blockIdx.y == 0) {
        const float* colmax_p = ws + WS_COLMAX;
        const float* colsum_p = ws + WS_COLSUM;
        const float* colssq_p = ws + WS_COLSSQ;
        const float* colp1_p  = ws + WS_COLP1;

        float m = -3.4e38f, sm = 0.f, sq = 0.f, p1 = 0.f;
#pragma unroll
        for (int t = 0; t < TILES; ++t) {
            size_t idx = ((size_t)b * TILES + t) * S + s;
            m = fmaxf(m, colmax_p[idx]);
            sm += colsum_p[idx];
            sq += colssq_p[idx];
            p1 += colp1_p[idx];
        }
        float mean  = sm * (1.f / L);
        float var   = (sq - sm * sm * (1.f / L)) * (1.f / (L - 1));
        float score = (m - mean) / sqrtf(var);

        float gmax = bred<true>(score, red);
        float e    = __expf(score - gmax);
        float esum = bred<false>(e, red);
        float sharp1 = e / esum;
        out[(size_t)b * S + s] = sharp1;
        float loss1 = bred<false>(sharp1 * p1, red);
        if (s == 0) atomicAdd(out + (size_t)B * S, loss1 * (0.5f / B));
    } else {
        const float* rowmax_p = ws + WS_ROWMAX;
        const float* rowsum_p = ws + WS_ROWSUM;
        const float* rowssq_p = ws + WS_ROWSSQ;
        const float* rowp2_p  = ws + WS_ROWP2;
        const float* negs_p   = ws + WS_NEGS;
        const float* negc_p   = ws + WS_NEGC;

        size_t ridx = ((size_t)b * L + s) * HALVES;
        float m2 = rowmax_p[ridx], sm2 = rowsum_p[ridx];
        float sq2 = rowssq_p[ridx], p2 = rowp2_p[ridx];
#pragma unroll
        for (int h = 1; h < HALVES; ++h) {
            m2 = fmaxf(m2, rowmax_p[ridx + h]);
            sm2 += rowsum_p[ridx + h];
            sq2 += rowssq_p[ridx + h];
            p2  += rowp2_p[ridx + h];
        }
        float mean2  = sm2 * (1.f / S);
        float var2   = (sq2 - sm2 * sm2 * (1.f / S)) * (1.f / (S - 1));
        float score2 = (m2 - mean2) / sqrtf(var2);

        float gmax2 = bred<true>(score2, red);
        float e2    = __expf(score2 - gmax2);
        float esum2 = bred<false>(e2, red);
        float loss2 = bred<false>((e2 / esum2) * p2, red);

        if (s == 0) {
            float ns = 0.f, nc = 0.f;
            for (int t = 0; t < TILES * HALVES; ++t) {
                ns += negs_p[b * TILES * HALVES + t];
                nc += negc_p[b * TILES * HALVES + t];
            }
            atomicAdd(out + (size_t)B * S, (0.5f * loss2 + ns / nc) * (1.f / B));
        }
    }
}

extern "C" void kernel_launch(void* const* d_in, const int* in_sizes, int n_in,
                              void* d_out, int out_size, void* d_ws, size_t ws_size,
                              hipStream_t stream)
{
    const float* q      = (const float*)d_in[0];
    const float* k      = (const float*)d_in[1];
    const int*   labels = (const int*)d_in[2];
    float* out = (float*)d_out;
    float* ws  = (float*)d_ws;

    // zero the scalar-loss slot (harness poisons d_out before timed replays)
    hipMemsetAsync((char*)d_out + (size_t)B * S * sizeof(float), 0, sizeof(float), stream);

    convert_kernel<<<dim3(B * (TILES + NCHUNK)), dim3(256), 0, stream>>>(q, k, ws);
    pass1_kernel<<<dim3(B * TILES * HALVES), dim3(256), 0, stream>>>(labels, ws);
    pass2_kernel<<<dim3(B, 2), dim3(512), 0, stream>>>(ws, out);
}